// Round 11
// baseline (612.504 us; speedup 1.0000x reference)
//
#include <hip/hip_runtime.h>
#include <hip/hip_cooperative_groups.h>

namespace cg = cooperative_groups;

#define CD 1024
#define NB 4096

typedef __attribute__((ext_vector_type(8))) short short8;
typedef __attribute__((ext_vector_type(4))) short short4v;
typedef __attribute__((ext_vector_type(4))) float f32x4;
typedef __attribute__((ext_vector_type(4))) int int4v;

typedef __attribute__((address_space(1))) const void gv_t;
typedef __attribute__((address_space(3))) void lv_t;
#define GLOAD16(g, l) __builtin_amdgcn_global_load_lds((gv_t*)(g), (lv_t*)(l), 16, 0, 0)
#define MF(a, b, c) __builtin_amdgcn_mfma_f32_16x16x32_bf16((a), (b), (c), 0, 0, 0)

__device__ __forceinline__ short f2bf(float f) {
  unsigned u = __float_as_uint(f);
  u = (u + 0x7FFFu + ((u >> 16) & 1u)) >> 16;
  return (short)u;
}
__device__ __forceinline__ float bf2f(short s) {
  return __uint_as_float(((unsigned)(unsigned short)s) << 16);
}

// ---- GEMM phase: out[4096,1024] = Act @ W^T (R7's proven best structure:
// BM=BN=128, BK=128 as two 64-halves, 8 waves, wave-tile 64x32, LDS 128KB
// dbuf, 2-phase __syncthreads schedule, pre-swizzled staging, swapped-operand
// MFMA). epi: 0 = relu->bf16, 2 = +res->bf16, 3 = +res->f32
__device__ __noinline__ void gemm_layer(const short* __restrict__ Act,
                                        const short* __restrict__ W,
                                        const short* __restrict__ Res,
                                        void* __restrict__ Out, int epi,
                                        short* ldsA, short* ldsB) {
  const int tid = threadIdx.x;
  const int lane = tid & 63;
  const int wid = tid >> 6;
  const int wr = wid >> 2;                 // 0..1 : 64-row slice
  const int wc = wid & 3;                  // 0..3 : 32-col slice
  const int f = blockIdx.x;
  const int xcd = f & 7, c = f >> 3;
  const int m0 = (((xcd << 2) | (c & 3)) << 7);  // 32 M-tiles
  const int o0 = ((c >> 2) << 7);                // 8 O-tiles

  const short* aptr[2][2];
  const short* bptr[2][2];
#pragma unroll
  for (int h = 0; h < 2; ++h)
#pragma unroll
    for (int i = 0; i < 2; ++i) {
      int cc = tid + (i << 9);
      int row = cc >> 3;
      int ch = (cc & 7) ^ (row & 7);
      aptr[h][i] = Act + (long)(m0 + row) * CD + (h << 6) + (ch << 3);
      bptr[h][i] = W + (long)(o0 + row) * CD + (h << 6) + (ch << 3);
    }

  auto stage = [&](int t, int buf) {
    const int koff = t << 7;
#pragma unroll
    for (int h = 0; h < 2; ++h)
#pragma unroll
      for (int i = 0; i < 2; ++i) {
        GLOAD16(aptr[h][i] + koff, ldsA + ((buf << 1) + h) * 8192 + ((tid + (i << 9)) << 3));
        GLOAD16(bptr[h][i] + koff, ldsB + ((buf << 1) + h) * 8192 + ((tid + (i << 9)) << 3));
      }
  };

  f32x4 acc[4][2] = {};
  const int frow = lane & 15;
  const int fch = lane >> 4;               // 0..3
  const int fsw = lane & 7;

  stage(0, 0);
  for (int t = 0; t < 8; ++t) {
    __syncthreads();                       // buf[t&1] staged (drains vmcnt)
    if (t < 7) stage(t + 1, (t + 1) & 1);
#pragma unroll
    for (int kk = 0; kk < 4; ++kk) {
      const short* La = ldsA + (((t & 1) << 1) + (kk >> 1)) * 8192;
      const short* Lb = ldsB + (((t & 1) << 1) + (kk >> 1)) * 8192;
      const int chsw = (((kk & 1) << 2) + fch) ^ fsw;
      short8 af[4], wf[2];
#pragma unroll
      for (int m = 0; m < 4; ++m) {
        int row = (wr << 6) + (m << 4) + frow;
        af[m] = *(const short8*)(La + (row << 6) + (chsw << 3));
      }
#pragma unroll
      for (int n = 0; n < 2; ++n) {
        int row = (wc << 5) + (n << 4) + frow;
        wf[n] = *(const short8*)(Lb + (row << 6) + (chsw << 3));
      }
#pragma unroll
      for (int m = 0; m < 4; ++m)
#pragma unroll
        for (int n = 0; n < 2; ++n)
          acc[m][n] = MF(wf[n], af[m], acc[m][n]);
    }
  }
  __syncthreads();                         // last tile's MFMAs use LDS; keep safe vs caller reuse

  // epilogue (swapped operands): lane&15 = M-row, (lane>>4)*4+reg = out-col
  const int orow = m0 + (wr << 6) + frow;
  const int ocol = o0 + (wc << 5) + (fch << 2);
#pragma unroll
  for (int m = 0; m < 4; ++m) {
#pragma unroll
    for (int n = 0; n < 2; ++n) {
      long row = orow + (m << 4);
      int col = ocol + (n << 4);
      f32x4 v = acc[m][n];
      if (epi == 0) {
        short4v ov;
        ov[0] = f2bf(fmaxf(v[0], 0.0f));
        ov[1] = f2bf(fmaxf(v[1], 0.0f));
        ov[2] = f2bf(fmaxf(v[2], 0.0f));
        ov[3] = f2bf(fmaxf(v[3], 0.0f));
        *(short4v*)((short*)Out + row * CD + col) = ov;
      } else if (epi == 2) {
        short4v rv = *(const short4v*)(Res + row * CD + col);
        short4v ov;
        ov[0] = f2bf(v[0] + bf2f(rv[0]));
        ov[1] = f2bf(v[1] + bf2f(rv[1]));
        ov[2] = f2bf(v[2] + bf2f(rv[2]));
        ov[3] = f2bf(v[3] + bf2f(rv[3]));
        *(short4v*)((short*)Out + row * CD + col) = ov;
      } else {
        short4v rv = *(const short4v*)(Res + row * CD + col);
        f32x4 ov;
        ov[0] = v[0] + bf2f(rv[0]);
        ov[1] = v[1] + bf2f(rv[1]);
        ov[2] = v[2] + bf2f(rv[2]);
        ov[3] = v[3] + bf2f(rv[3]);
        *(f32x4*)((float*)Out + row * CD + col) = ov;
      }
    }
  }
}

// ---- LayerNorm phase: 16 rows per block, 2 rows per iteration (512 thr) ----
__device__ __noinline__ void ln_16rows(const short* __restrict__ in,
                                       short* __restrict__ out,
                                       const float* __restrict__ g,
                                       const float* __restrict__ b,
                                       float* red) {
  const int tid = threadIdx.x;
  const int half = tid >> 8;               // row within pair
  const int tin = tid & 255;
  const int wid = tid >> 6;                // 0..7
  const int k = tin << 2;
  for (int it = 0; it < 8; ++it) {
    long row = (blockIdx.x << 4) + (it << 1) + half;
    short4v v = *(const short4v*)(in + (row << 10) + k);
    float f0 = bf2f(v[0]), f1 = bf2f(v[1]), f2 = bf2f(v[2]), f3 = bf2f(v[3]);
    float s = f0 + f1 + f2 + f3;
    float q = f0 * f0 + f1 * f1 + f2 * f2 + f3 * f3;
#pragma unroll
    for (int off = 1; off < 64; off <<= 1) {
      s += __shfl_xor(s, off);
      q += __shfl_xor(q, off);
    }
    if ((tid & 63) == 0) { red[wid] = s; red[8 + wid] = q; }
    __syncthreads();
    int base = half << 2;
    s = red[base] + red[base + 1] + red[base + 2] + red[base + 3];
    q = red[8 + base] + red[9 + base] + red[10 + base] + red[11 + base];
    float mu = s * (1.0f / 1024.0f);
    float var = q * (1.0f / 1024.0f) - mu * mu;
    float rstd = rsqrtf(var + 1e-5f);
    short4v o;
    o[0] = f2bf((f0 - mu) * rstd * g[k] + b[k]);
    o[1] = f2bf((f1 - mu) * rstd * g[k + 1] + b[k + 1]);
    o[2] = f2bf((f2 - mu) * rstd * g[k + 2] + b[k + 2]);
    o[3] = f2bf((f3 - mu) * rstd * g[k + 3] + b[k + 3]);
    *(short4v*)(out + (row << 10) + k) = o;
    __syncthreads();                       // red reuse next iter
  }
}

// ---- the megakernel: prep + 12 GEMMs + 2 LNs with grid.sync between ----
__global__ __launch_bounds__(512, 1) void mega(const float* __restrict__ x,
                                               const int* __restrict__ q4,
                                               const float* __restrict__ nrm,
                                               const float* __restrict__ la,
                                               const float* __restrict__ lb,
                                               const float* __restrict__ lng,
                                               const float* __restrict__ lnb,
                                               short* Wb, short* buf0, short* buf1,
                                               short* buf2, short* buf3, float* outf) {
  cg::grid_group grid = cg::this_grid();
  __shared__ __align__(16) short ldsA[2 * 2 * 8192];
  __shared__ __align__(16) short ldsB[2 * 2 * 8192];
  __shared__ float red[16];
  const int gtid = blockIdx.x * 512 + threadIdx.x;

  // ---- prep: x f32 -> bf16 (4 iters/thread) ----
  for (int cc = gtid; cc < 524288; cc += 131072) {
    int i = cc << 3;
    f32x4 a = *(const f32x4*)(x + i);
    f32x4 b = *(const f32x4*)(x + i + 4);
    short8 o;
    o[0] = f2bf(a[0]); o[1] = f2bf(a[1]); o[2] = f2bf(a[2]); o[3] = f2bf(a[3]);
    o[4] = f2bf(b[0]); o[5] = f2bf(b[1]); o[6] = f2bf(b[2]); o[7] = f2bf(b[3]);
    *(short8*)(buf0 + i) = o;
  }
  // ---- prep: dequant 12 layers + fold LoRA (12 iters/thread) ----
  for (int tg = gtid; tg < 1572864; tg += 131072) {
    int w0 = tg * 4;
    int l = w0 >> 19;
    int wl = w0 & 524287;
    int g = wl >> 6;
    int j0 = wl & 63;
    int o = g >> 3;
    int kb = ((g & 7) << 7) + (j0 << 1);
    int4v q = *(const int4v*)(q4 + w0);
    float n = nrm[(l << 13) + g];
    float s = n * (2.0f / 15.0f);
    f32x4 B = *(const f32x4*)(lb + (((l << 10) + o) << 2));
    const float* A = la + (l << 12);
    float Ar[4][8];
#pragma unroll
    for (int r = 0; r < 4; ++r) {
      f32x4 u = *(const f32x4*)(A + r * CD + kb);
      f32x4 v = *(const f32x4*)(A + r * CD + kb + 4);
      Ar[r][0] = u[0]; Ar[r][1] = u[1]; Ar[r][2] = u[2]; Ar[r][3] = u[3];
      Ar[r][4] = v[0]; Ar[r][5] = v[1]; Ar[r][6] = v[2]; Ar[r][7] = v[3];
    }
    short8 outv;
#pragma unroll
    for (int p = 0; p < 8; ++p) {
      int qw = q[p >> 1];
      int nib = (qw >> ((p & 1) << 2)) & 15;
      float wv = (float)nib * s - n;
      wv += B[0] * Ar[0][p] + B[1] * Ar[1][p] + B[2] * Ar[2][p] + B[3] * Ar[3][p];
      outv[p] = f2bf(wv);
    }
    *(short8*)(Wb + (l << 20) + (o << 10) + kb) = outv;
  }
  grid.sync();

  short* W0 = Wb;
#define WL(l) (W0 + ((long)(l) << 20))
  // block 1
  gemm_layer(buf0, WL(0), nullptr, buf1, 0, ldsA, ldsB); grid.sync();
  gemm_layer(buf1, WL(1), nullptr, buf2, 0, ldsA, ldsB); grid.sync();
  gemm_layer(buf2, WL(2), buf0, buf3, 2, ldsA, ldsB);    grid.sync();
  ln_16rows(buf3, buf0, lng, lnb, red);                  grid.sync();
  // block 2
  gemm_layer(buf0, WL(3), nullptr, buf1, 0, ldsA, ldsB); grid.sync();
  gemm_layer(buf1, WL(4), nullptr, buf2, 0, ldsA, ldsB); grid.sync();
  gemm_layer(buf2, WL(5), buf0, buf3, 2, ldsA, ldsB);    grid.sync();
  // block 3
  gemm_layer(buf3, WL(6), nullptr, buf1, 0, ldsA, ldsB); grid.sync();
  gemm_layer(buf1, WL(7), nullptr, buf2, 0, ldsA, ldsB); grid.sync();
  gemm_layer(buf2, WL(8), buf3, buf0, 2, ldsA, ldsB);    grid.sync();
  ln_16rows(buf0, buf1, lng + CD, lnb + CD, red);        grid.sync();
  // block 4 (final layer writes f32 to d_out)
  gemm_layer(buf1, WL(9), nullptr, buf2, 0, ldsA, ldsB); grid.sync();
  gemm_layer(buf2, WL(10), nullptr, buf0, 0, ldsA, ldsB); grid.sync();
  gemm_layer(buf0, WL(11), buf1, outf, 3, ldsA, ldsB);
#undef WL
}

extern "C" void kernel_launch(void* const* d_in, const int* in_sizes, int n_in,
                              void* d_out, int out_size, void* d_ws, size_t ws_size,
                              hipStream_t stream) {
  const float* x = (const float*)d_in[0];
  const int* q4 = (const int*)d_in[1];
  const float* nrm = (const float*)d_in[2];
  const float* la = (const float*)d_in[3];
  const float* lb = (const float*)d_in[4];
  const float* lng = (const float*)d_in[5];
  const float* lnb = (const float*)d_in[6];

  short* Wb = (short*)d_ws;                             // 24 MB: 12 x [1024][1024] bf16
  short* buf0 = (short*)((char*)d_ws + (24u << 20));    // 8 MB
  short* buf1 = buf0 + (long)NB * CD;                   // 8 MB
  short* buf2 = (short*)d_out;                          // d_out lower 8 MB as bf16 scratch
  short* buf3 = buf2 + (long)NB * CD;                   // d_out upper 8 MB
  float* outf = (float*)d_out;

  void* args[] = {&x, &q4, &nrm, &la, &lb, &lng, &lnb,
                  &Wb, &buf0, &buf1, &buf2, &buf3, &outf};
  hipLaunchCooperativeKernel((void*)mega, dim3(256), dim3(512), args, 0, stream);
}

// Round 12
// 331.868 us; speedup vs baseline: 1.8456x; 1.8456x over previous
//
#include <hip/hip_runtime.h>

#define CD 1024
#define NB 4096

typedef __attribute__((ext_vector_type(8))) short short8;
typedef __attribute__((ext_vector_type(4))) short short4v;
typedef __attribute__((ext_vector_type(4))) float f32x4;
typedef __attribute__((ext_vector_type(4))) int int4v;

typedef __attribute__((address_space(1))) const void gv_t;
typedef __attribute__((address_space(3))) void lv_t;
#define GLOAD16(g, l) __builtin_amdgcn_global_load_lds((gv_t*)(g), (lv_t*)(l), 16, 0, 0)
#define MF(a, b, c) __builtin_amdgcn_mfma_f32_16x16x32_bf16((a), (b), (c), 0, 0, 0)

__device__ __forceinline__ short f2bf(float f) {
  unsigned u = __float_as_uint(f);
  u = (u + 0x7FFFu + ((u >> 16) & 1u)) >> 16;
  return (short)u;
}
__device__ __forceinline__ float bf2f(short s) {
  return __uint_as_float(((unsigned)(unsigned short)s) << 16);
}

// ---- fused: x f32->bf16 (blocks 0..2047) + dequant12+LoRA-fold (blocks 2048..8191) ----
__global__ __launch_bounds__(256) void prep_kernel(const float* __restrict__ x,
                                                   short* __restrict__ xb,
                                                   const int* __restrict__ q4,
                                                   const float* __restrict__ nrm,
                                                   const float* __restrict__ la,
                                                   const float* __restrict__ lb,
                                                   short* __restrict__ Wb) {
  int bid = blockIdx.x;
  if (bid < 2048) {
    int i = (bid * 256 + threadIdx.x) * 8;
    f32x4 a = *(const f32x4*)(x + i);
    f32x4 b = *(const f32x4*)(x + i + 4);
    short8 o;
    o[0] = f2bf(a[0]); o[1] = f2bf(a[1]); o[2] = f2bf(a[2]); o[3] = f2bf(a[3]);
    o[4] = f2bf(b[0]); o[5] = f2bf(b[1]); o[6] = f2bf(b[2]); o[7] = f2bf(b[3]);
    *(short8*)(xb + i) = o;
    return;
  }
  int tidg = (bid - 2048) * 256 + threadIdx.x;
  int w0 = tidg * 4;
  int l = w0 >> 19;
  int wl = w0 & 524287;
  int g = wl >> 6;
  int j0 = wl & 63;
  int o = g >> 3;
  int kb = ((g & 7) << 7) + (j0 << 1);
  int4v q = *(const int4v*)(q4 + w0);
  float n = nrm[(l << 13) + g];
  float s = n * (2.0f / 15.0f);
  f32x4 B = *(const f32x4*)(lb + (((l << 10) + o) << 2));
  const float* A = la + (l << 12);
  float Ar[4][8];
#pragma unroll
  for (int r = 0; r < 4; ++r) {
    f32x4 u = *(const f32x4*)(A + r * CD + kb);
    f32x4 v = *(const f32x4*)(A + r * CD + kb + 4);
    Ar[r][0] = u[0]; Ar[r][1] = u[1]; Ar[r][2] = u[2]; Ar[r][3] = u[3];
    Ar[r][4] = v[0]; Ar[r][5] = v[1]; Ar[r][6] = v[2]; Ar[r][7] = v[3];
  }
  short8 outv;
#pragma unroll
  for (int p = 0; p < 8; ++p) {
    int qw = q[p >> 1];
    int nib = (qw >> ((p & 1) << 2)) & 15;
    float wv = (float)nib * s - n;
    wv += B[0] * Ar[0][p] + B[1] * Ar[1][p] + B[2] * Ar[2][p] + B[3] * Ar[3][p];
    outv[p] = f2bf(wv);
  }
  *(short8*)(Wb + (l << 20) + (o << 10) + kb) = outv;
}

// ---- GEMM: out[M,O] = Act[M,K] @ W[O,K]^T, bf16 in, f32 acc ----
// A/B vs R7: waves 8->4 (wave-tile 64x64, minimum LDS frag traffic per CU:
// 512 rows-equiv vs R7's 768), BK=128 kept (8 barrier drains). Everything
// else identical: BM=BN=128, LDS 128KB dbuf (2 x 64-k halves, R1-layout each),
// pre-swizzled staging, 2-phase __syncthreads schedule, grid 256 = 1 block/CU,
// XCD 4x8 patch map, swapped-operand MFMA.
// EPI: 0 = relu->bf16, 2 = +resid->bf16, 3 = +resid->f32
template <int EPI>
__global__ __launch_bounds__(256) void qgemm(const short* __restrict__ Act,
                                             const short* __restrict__ W,
                                             const short* __restrict__ Res,
                                             void* __restrict__ Out) {
  __shared__ __align__(16) short ldsA[2][2][128 * 64];  // [buf][half][row][k]
  __shared__ __align__(16) short ldsB[2][2][128 * 64];
  const int tid = threadIdx.x;
  const int lane = tid & 63;
  const int wid = tid >> 6;                // 0..3
  const int wr = wid >> 1, wc = wid & 1;   // wave-tile 64x64
  const int f = blockIdx.x;
  const int xcd = f & 7, c = f >> 3;
  const int m0 = (((xcd << 2) | (c & 3)) << 7);  // 32 M-tiles
  const int o0 = ((c >> 2) << 7);                // 8 O-tiles

  // staging: per half h, i=0..3: chunk cc = tid + i*256 covers [128r][8ch];
  // source pre-swizzled ch ^= row&7; LDS dest linear.
  const short* aptr[2][4];
  const short* bptr[2][4];
#pragma unroll
  for (int h = 0; h < 2; ++h)
#pragma unroll
    for (int i = 0; i < 4; ++i) {
      int cc = tid + (i << 8);
      int row = cc >> 3;
      int ch = (cc & 7) ^ (row & 7);
      aptr[h][i] = Act + (long)(m0 + row) * CD + (h << 6) + (ch << 3);
      bptr[h][i] = W + (long)(o0 + row) * CD + (h << 6) + (ch << 3);
    }

  auto stage = [&](int t, int buf) {
    const int koff = t << 7;
#pragma unroll
    for (int h = 0; h < 2; ++h)
#pragma unroll
      for (int i = 0; i < 4; ++i) {
        GLOAD16(aptr[h][i] + koff, &ldsA[buf][h][(tid + (i << 8)) << 3]);
        GLOAD16(bptr[h][i] + koff, &ldsB[buf][h][(tid + (i << 8)) << 3]);
      }
  };

  f32x4 acc[4][4] = {};
  const int frow = lane & 15;
  const int fch = lane >> 4;               // 0..3
  const int fsw = lane & 7;

  stage(0, 0);
  for (int t = 0; t < 8; ++t) {
    __syncthreads();                       // buf[t&1] staged (drains vmcnt)
    if (t < 7) stage(t + 1, (t + 1) & 1);
#pragma unroll
    for (int kk = 0; kk < 4; ++kk) {
      const short* La = ldsA[t & 1][kk >> 1];
      const short* Lb = ldsB[t & 1][kk >> 1];
      const int chsw = (((kk & 1) << 2) + fch) ^ fsw;
      short8 af[4], wf[4];
#pragma unroll
      for (int m = 0; m < 4; ++m) {
        int row = (wr << 6) + (m << 4) + frow;
        af[m] = *(const short8*)(La + (row << 6) + (chsw << 3));
      }
#pragma unroll
      for (int n = 0; n < 4; ++n) {
        int row = (wc << 6) + (n << 4) + frow;
        wf[n] = *(const short8*)(Lb + (row << 6) + (chsw << 3));
      }
#pragma unroll
      for (int m = 0; m < 4; ++m)
#pragma unroll
        for (int n = 0; n < 4; ++n)
          acc[m][n] = MF(wf[n], af[m], acc[m][n]);
    }
  }

  // epilogue (swapped operands): lane&15 = M-row, (lane>>4)*4+reg = out-col
  const int orow = m0 + (wr << 6) + frow;
  const int ocol = o0 + (wc << 6) + (fch << 2);
#pragma unroll
  for (int m = 0; m < 4; ++m) {
#pragma unroll
    for (int n = 0; n < 4; ++n) {
      long row = orow + (m << 4);
      int col = ocol + (n << 4);
      f32x4 v = acc[m][n];
      if (EPI == 0) {
        short4v ov;
        ov[0] = f2bf(fmaxf(v[0], 0.0f));
        ov[1] = f2bf(fmaxf(v[1], 0.0f));
        ov[2] = f2bf(fmaxf(v[2], 0.0f));
        ov[3] = f2bf(fmaxf(v[3], 0.0f));
        *(short4v*)((short*)Out + row * CD + col) = ov;
      } else if (EPI == 2) {
        short4v rv = *(const short4v*)(Res + row * CD + col);
        short4v ov;
        ov[0] = f2bf(v[0] + bf2f(rv[0]));
        ov[1] = f2bf(v[1] + bf2f(rv[1]));
        ov[2] = f2bf(v[2] + bf2f(rv[2]));
        ov[3] = f2bf(v[3] + bf2f(rv[3]));
        *(short4v*)((short*)Out + row * CD + col) = ov;
      } else {
        short4v rv = *(const short4v*)(Res + row * CD + col);
        f32x4 ov;
        ov[0] = v[0] + bf2f(rv[0]);
        ov[1] = v[1] + bf2f(rv[1]);
        ov[2] = v[2] + bf2f(rv[2]);
        ov[3] = v[3] + bf2f(rv[3]);
        *(f32x4*)((float*)Out + row * CD + col) = ov;
      }
    }
  }
}

// ---- LayerNorm over rows of 1024 bf16 ----
__global__ __launch_bounds__(256) void ln_kernel(const short* __restrict__ in,
                                                 short* __restrict__ out,
                                                 const float* __restrict__ g,
                                                 const float* __restrict__ b) {
  __shared__ float rs_[4], rq_[4];
  int row = blockIdx.x, tid = threadIdx.x;
  int k = tid * 4;
  short4v v = *(const short4v*)(in + (long)row * CD + k);
  float f0 = bf2f(v[0]), f1 = bf2f(v[1]), f2 = bf2f(v[2]), f3 = bf2f(v[3]);
  float s = f0 + f1 + f2 + f3;
  float q = f0 * f0 + f1 * f1 + f2 * f2 + f3 * f3;
#pragma unroll
  for (int off = 1; off < 64; off <<= 1) {
    s += __shfl_xor(s, off);
    q += __shfl_xor(q, off);
  }
  if ((tid & 63) == 0) { rs_[tid >> 6] = s; rq_[tid >> 6] = q; }
  __syncthreads();
  s = rs_[0] + rs_[1] + rs_[2] + rs_[3];
  q = rq_[0] + rq_[1] + rq_[2] + rq_[3];
  float mu = s * (1.0f / 1024.0f);
  float var = q * (1.0f / 1024.0f) - mu * mu;
  float rstd = rsqrtf(var + 1e-5f);
  short4v o;
  o[0] = f2bf((f0 - mu) * rstd * g[k] + b[k]);
  o[1] = f2bf((f1 - mu) * rstd * g[k + 1] + b[k + 1]);
  o[2] = f2bf((f2 - mu) * rstd * g[k + 2] + b[k + 2]);
  o[3] = f2bf((f3 - mu) * rstd * g[k + 3] + b[k + 3]);
  *(short4v*)(out + (long)row * CD + k) = o;
}

extern "C" void kernel_launch(void* const* d_in, const int* in_sizes, int n_in,
                              void* d_out, int out_size, void* d_ws, size_t ws_size,
                              hipStream_t stream) {
  const float* x = (const float*)d_in[0];
  const int* q4 = (const int*)d_in[1];
  const float* nrm = (const float*)d_in[2];
  const float* la = (const float*)d_in[3];
  const float* lb = (const float*)d_in[4];
  const float* lng = (const float*)d_in[5];
  const float* lnb = (const float*)d_in[6];

  short* Wb = (short*)d_ws;                             // 24 MB: 12 x [1024][1024] bf16
  short* buf0 = (short*)((char*)d_ws + (24u << 20));    // 8 MB
  short* buf1 = buf0 + (long)NB * CD;                   // 8 MB
  short* buf2 = (short*)d_out;                          // d_out lower 8 MB as bf16 scratch
  short* buf3 = buf2 + (long)NB * CD;                   // d_out upper 8 MB
  float* outf = (float*)d_out;

  prep_kernel<<<dim3(8192), dim3(256), 0, stream>>>(x, buf0, q4, nrm, la, lb, Wb);

  dim3 gg(256), bb(256);
  auto Wl = [&](int l) { return Wb + ((long)l << 20); };

  // block 1 (input xb = buf0, resid buf0)
  qgemm<0><<<gg, bb, 0, stream>>>(buf0, Wl(0), nullptr, buf1);
  qgemm<0><<<gg, bb, 0, stream>>>(buf1, Wl(1), nullptr, buf2);
  qgemm<2><<<gg, bb, 0, stream>>>(buf2, Wl(2), buf0, buf3);
  ln_kernel<<<dim3(4096), dim3(256), 0, stream>>>(buf3, buf0, lng, lnb);
  // block 2 (input/resid buf0)
  qgemm<0><<<gg, bb, 0, stream>>>(buf0, Wl(3), nullptr, buf1);
  qgemm<0><<<gg, bb, 0, stream>>>(buf1, Wl(4), nullptr, buf2);
  qgemm<2><<<gg, bb, 0, stream>>>(buf2, Wl(5), buf0, buf3);
  // block 3 (input/resid buf3)
  qgemm<0><<<gg, bb, 0, stream>>>(buf3, Wl(6), nullptr, buf1);
  qgemm<0><<<gg, bb, 0, stream>>>(buf1, Wl(7), nullptr, buf2);
  qgemm<2><<<gg, bb, 0, stream>>>(buf2, Wl(8), buf3, buf0);
  ln_kernel<<<dim3(4096), dim3(256), 0, stream>>>(buf0, buf1, lng + CD, lnb + CD);
  // block 4 (input/resid buf1), final layer writes f32 to d_out
  qgemm<0><<<gg, bb, 0, stream>>>(buf1, Wl(9), nullptr, buf2);
  qgemm<0><<<gg, bb, 0, stream>>>(buf2, Wl(10), nullptr, buf0);
  qgemm<3><<<gg, bb, 0, stream>>>(buf0, Wl(11), buf1, (void*)outf);
}